// Round 5
// baseline (208.312 us; speedup 1.0000x reference)
//
#include <hip/hip_runtime.h>
#include <hip/hip_fp16.h>

#define NTHREADS 256
#define MAIN_NBLOCKS 1024
#define FB_NBLOCKS 2048

// Folded constants:
//   KTOT = sqrt(2) * 1.14136 * e^2     (sqrt(10) in emb cancels /sqrt(10) before relu;
//                                       relu positively homogeneous -> sqrt(2) folds in)
//   CL_l = PATH_C_l * 0.25 * (1/sqrt(10))   (w = h@W2/sqrt(16), node scale 1/sqrt(10))
//   SH scale factors (S3, S5*S3, S5, 0.5*S5*S3) folded into the packed fp16 table.
#define KTOT 11.9269705f
#define CL0  0.04564355f
#define CL1  0.02635231f
#define CL2  0.02041241f
#define S3   1.7320508f
#define S5   2.2360680f

__device__ __forceinline__ float fast_rcp(float x) { return __builtin_amdgcn_rcpf(x); }
__device__ __forceinline__ float sfl(float x) {
    return __uint_as_float(__builtin_amdgcn_readfirstlane(__float_as_uint(x)));
}

typedef float vfloat4 __attribute__((ext_vector_type(4)));
typedef int   vint4   __attribute__((ext_vector_type(4)));
__device__ __forceinline__ float4 ntload4(const float4* p) {
    vfloat4 v = __builtin_nontemporal_load((const vfloat4*)p);
    return make_float4(v.x, v.y, v.z, v.w);
}
__device__ __forceinline__ int4 ntloadi4(const int4* p) {
    vint4 v = __builtin_nontemporal_load((const vint4*)p);
    return make_int4(v.x, v.y, v.z, v.w);
}

// ---------- prep: node_feats [N][9] f32 -> tableA [N][8] f16 (16B, SH-scaled) + tableB [N] f16 ----------
__global__ __launch_bounds__(256) void pack_feats_kernel(
    const float* __restrict__ nf, uint4* __restrict__ tableA,
    __half* __restrict__ tableB, int n_nodes)
{
    const int n = blockIdx.x * 256 + threadIdx.x;
    if (n >= n_nodes) return;
    const float* f = nf + 9 * (size_t)n;
    const float c0 = 1.0f, c1 = S3, c2 = S3, c3 = S3;
    const float c4 = S5 * S3, c5 = S5 * S3, c6 = S5, c7 = S5 * S3;
    unsigned u[4];
    {
        __half2 h; h.x = __float2half_rn(f[0] * c0); h.y = __float2half_rn(f[1] * c1);
        u[0] = *reinterpret_cast<unsigned*>(&h);
    }
    {
        __half2 h; h.x = __float2half_rn(f[2] * c2); h.y = __float2half_rn(f[3] * c3);
        u[1] = *reinterpret_cast<unsigned*>(&h);
    }
    {
        __half2 h; h.x = __float2half_rn(f[4] * c4); h.y = __float2half_rn(f[5] * c5);
        u[2] = *reinterpret_cast<unsigned*>(&h);
    }
    {
        __half2 h; h.x = __float2half_rn(f[6] * c6); h.y = __float2half_rn(f[7] * c7);
        u[3] = *reinterpret_cast<unsigned*>(&h);
    }
    tableA[n] = make_uint4(u[0], u[1], u[2], u[3]);
    tableB[n] = __float2half_rn(f[8] * (0.5f * S5 * S3));
}

__device__ __forceinline__ float2 cvt2(unsigned u) {
    __half2 h = *reinterpret_cast<__half2*>(&u);
    return __half22float2(h);
}

// ---------- per-edge term; g0/f8p are SH-prescaled gathered feats ----------
__device__ __forceinline__ float edge_term(
    float vx, float vy, float vz, uint4 g0, float f8p,
    const float4* __restrict__ sW1v, const float4 (&w2c)[3][4])
{
    const float r2 = fmaf(vx, vx, fmaf(vy, vy, vz * vz));
    const float rs = rsqrtf(fmaxf(r2, 1e-24f));
    const float r  = r2 * rs;
    const float x = vx * rs, y = vy * rs, z = vz * rs;

    // radial smooth_finite: <=2 active bases, no inf anywhere
    const float t    = 11.0f * r;
    const int   k0   = (int)t;
    const float frac = t - (float)k0;
    float ea = 0.0f, eb = 0.0f;
    if (k0 >= 1 && k0 <= 10) {
        const float da = fmaf(-frac, frac, 1.0f);          // 1 - frac^2
        if (da > 0.0226f) ea = KTOT * __expf(-2.0f * fast_rcp(da));
    }
    if (k0 <= 9) {
        const float db = frac * (2.0f - frac);
        if (db > 0.0226f) eb = KTOT * __expf(-2.0f * fast_rcp(db));
    }

    const int ra = min(max(k0 - 1, 0), 9);
    const int rb = min(k0, 9);
    const float4* rowA = sW1v + ra * 5;
    const float4* rowB = sW1v + rb * 5;
    float4 av0 = make_float4(0.f, 0.f, 0.f, 0.f);
    float4 av1 = av0, av2 = av0;
#pragma unroll
    for (int q = 0; q < 4; ++q) {
        const float4 A = rowA[q];
        const float4 B = rowB[q];
        float4 h;
        h.x = fmaxf(fmaf(ea, A.x, eb * B.x), 0.0f);
        h.y = fmaxf(fmaf(ea, A.y, eb * B.y), 0.0f);
        h.z = fmaxf(fmaf(ea, A.z, eb * B.z), 0.0f);
        h.w = fmaxf(fmaf(ea, A.w, eb * B.w), 0.0f);
        const float4 c0 = w2c[0][q], c1 = w2c[1][q], c2 = w2c[2][q];
        av0.x = fmaf(h.x, c0.x, av0.x); av0.y = fmaf(h.y, c0.y, av0.y);
        av0.z = fmaf(h.z, c0.z, av0.z); av0.w = fmaf(h.w, c0.w, av0.w);
        av1.x = fmaf(h.x, c1.x, av1.x); av1.y = fmaf(h.y, c1.y, av1.y);
        av1.z = fmaf(h.z, c1.z, av1.z); av1.w = fmaf(h.w, c1.w, av1.w);
        av2.x = fmaf(h.x, c2.x, av2.x); av2.y = fmaf(h.y, c2.y, av2.y);
        av2.z = fmaf(h.z, c2.z, av2.z); av2.w = fmaf(h.w, c2.w, av2.w);
    }
    const float wv0 = (av0.x + av0.y) + (av0.z + av0.w);
    const float wv1 = (av1.x + av1.y) + (av1.z + av1.w);
    const float wv2 = (av2.x + av2.y) + (av2.z + av2.w);

    const float2 f01 = cvt2(g0.x);   // f0,       S3*f1
    const float2 f23 = cvt2(g0.y);   // S3*f2,    S3*f3
    const float2 f45 = cvt2(g0.z);   // S5S3*f4,  S5S3*f5
    const float2 f67 = cvt2(g0.w);   // S5*f6,    S5S3*f7

    const float dots0 = f01.x;
    const float dots1 = fmaf(f01.y, x, fmaf(f23.x, y, f23.y * z));
    const float xx = x * x, yy = y * y, zz = z * z;
    const float dots2 = fmaf(f45.x, x * z, fmaf(f45.y, x * y,
                        fmaf(f67.x, fmaf(-0.5f, xx + zz, yy),
                        fmaf(f67.y, y * z, f8p * (zz - xx)))));

    return fmaf(wv0, dots0, fmaf(wv1, dots1, wv2 * dots2));
}

// ---------- main: fully-resident grid, software-pipelined grid-stride loop ----------
__global__ __launch_bounds__(NTHREADS, 4) void edge_sum_packed(
    const float4* __restrict__ ev4,
    const int4*   __restrict__ src4,
    const uint4*  __restrict__ tableA,
    const __half* __restrict__ tableB,
    const float*  __restrict__ W1,
    const float*  __restrict__ W2,
    float*        __restrict__ block_sums,
    int n_edges)
{
    __shared__ float4 sW1[10][5];
    float* sW1f = reinterpret_cast<float*>(sW1);
    const int tid = threadIdx.x;
    if (tid < 160) {
        sW1f[(tid >> 4) * 20 + (tid & 15)] = W1[tid];
    } else if (tid < 200) {
        const int i = tid - 160;
        sW1f[(i >> 2) * 20 + 16 + (i & 3)] = 0.0f;
    }
    __syncthreads();

    // W2 cols with CL folded, forced to SGPRs (lane-uniform) via readfirstlane
    float4 w2c[3][4];
#pragma unroll
    for (int q = 0; q < 4; ++q) {
        w2c[0][q] = make_float4(sfl(W2[(4*q+0)*3+0] * CL0), sfl(W2[(4*q+1)*3+0] * CL0),
                                sfl(W2[(4*q+2)*3+0] * CL0), sfl(W2[(4*q+3)*3+0] * CL0));
        w2c[1][q] = make_float4(sfl(W2[(4*q+0)*3+1] * CL1), sfl(W2[(4*q+1)*3+1] * CL1),
                                sfl(W2[(4*q+2)*3+1] * CL1), sfl(W2[(4*q+3)*3+1] * CL1));
        w2c[2][q] = make_float4(sfl(W2[(4*q+0)*3+2] * CL2), sfl(W2[(4*q+1)*3+2] * CL2),
                                sfl(W2[(4*q+2)*3+2] * CL2), sfl(W2[(4*q+3)*3+2] * CL2));
    }

    const float4* sW1v = &sW1[0][0];
    float acc = 0.0f;
    const int n_groups = (n_edges + 3) >> 2;
    const int stride = gridDim.x * NTHREADS;
    int g = blockIdx.x * NTHREADS + tid;
    bool valid = (g < n_groups);
    bool fullg = valid && ((g << 2) + 4 <= n_edges);
    float4 a, b, c; int4 s;
    if (fullg) {
        a = ntload4(ev4 + 3 * (size_t)g);
        b = ntload4(ev4 + 3 * (size_t)g + 1);
        c = ntload4(ev4 + 3 * (size_t)g + 2);
        s = ntloadi4(src4 + g);
    }

    while (valid) {
        // gathers for current group (L2-resident tables)
        uint4 gA0, gA1, gA2, gA3;
        float f80 = 0.f, f81 = 0.f, f82 = 0.f, f83 = 0.f;
        if (fullg) {
            gA0 = tableA[s.x]; gA1 = tableA[s.y];
            gA2 = tableA[s.z]; gA3 = tableA[s.w];
            f80 = __half2float(tableB[s.x]); f81 = __half2float(tableB[s.y]);
            f82 = __half2float(tableB[s.z]); f83 = __half2float(tableB[s.w]);
        }
        // prefetch next group's stream data (hidden under this group's compute)
        const int  gn = g + stride;
        const bool vn = (gn < n_groups);
        const bool fn = vn && ((gn << 2) + 4 <= n_edges);
        float4 an, bn, cn; int4 sn;
        if (fn) {
            an = ntload4(ev4 + 3 * (size_t)gn);
            bn = ntload4(ev4 + 3 * (size_t)gn + 1);
            cn = ntload4(ev4 + 3 * (size_t)gn + 2);
            sn = ntloadi4(src4 + gn);
        }

        if (fullg) {
            acc += edge_term(a.x, a.y, a.z, gA0, f80, sW1v, w2c);
            acc += edge_term(a.w, b.x, b.y, gA1, f81, sW1v, w2c);
            acc += edge_term(b.z, b.w, c.x, gA2, f82, sW1v, w2c);
            acc += edge_term(c.y, c.z, c.w, gA3, f83, sW1v, w2c);
        } else {
            // partial last group (only exists when n_edges % 4 != 0)
            const float* evf  = reinterpret_cast<const float*>(ev4);
            const int*   srci = reinterpret_cast<const int*>(src4);
            for (int e = (g << 2); e < n_edges; ++e) {
                const int si = srci[e];
                acc += edge_term(evf[3 * (size_t)e], evf[3 * (size_t)e + 1],
                                 evf[3 * (size_t)e + 2], tableA[si],
                                 __half2float(tableB[si]), sW1v, w2c);
            }
        }
        a = an; b = bn; c = cn; s = sn;
        g = gn; valid = vn; fullg = fn;
    }

    // deterministic block reduction
#pragma unroll
    for (int off = 1; off < 64; off <<= 1)
        acc += __shfl_xor(acc, off, 64);
    __shared__ float wsum[NTHREADS / 64];
    const int lane = tid & 63, wid = tid >> 6;
    if (lane == 0) wsum[wid] = acc;
    __syncthreads();
    if (tid == 0) {
        float ssum = 0.0f;
#pragma unroll
        for (int w = 0; w < NTHREADS / 64; ++w) ssum += wsum[w];
        block_sums[blockIdx.x] = ssum;
    }
}

// ---------- fallback (round-2 proven structure, f32 scalar gather) ----------
__global__ __launch_bounds__(NTHREADS) void edge_sum_fallback(
    const float* __restrict__ node_feats,
    const float* __restrict__ edge_vec,
    const float* __restrict__ W1,
    const float* __restrict__ W2,
    const int*   __restrict__ edge_src,
    float*       __restrict__ block_sums,
    int n_edges)
{
    __shared__ float4 sW1[10][5];
    float* sW1f = reinterpret_cast<float*>(sW1);
    const int tid = threadIdx.x;
    if (tid < 160) {
        sW1f[(tid >> 4) * 20 + (tid & 15)] = W1[tid];
    } else if (tid < 200) {
        const int i = tid - 160;
        sW1f[(i >> 2) * 20 + 16 + (i & 3)] = 0.0f;
    }
    __syncthreads();

    float w2r[16][3];
#pragma unroll
    for (int j = 0; j < 16; ++j) {
        w2r[j][0] = W2[j * 3 + 0] * CL0;
        w2r[j][1] = W2[j * 3 + 1] * CL1;
        w2r[j][2] = W2[j * 3 + 2] * CL2;
    }

    float acc = 0.0f;
    const int stride = gridDim.x * blockDim.x;
    for (int e = blockIdx.x * blockDim.x + tid; e < n_edges; e += stride) {
        const float vx = edge_vec[3 * (size_t)e + 0];
        const float vy = edge_vec[3 * (size_t)e + 1];
        const float vz = edge_vec[3 * (size_t)e + 2];
        const int   src = edge_src[e];
        const float* f = node_feats + 9 * (size_t)src;
        const float r2 = fmaf(vx, vx, fmaf(vy, vy, vz * vz));
        const float rs = rsqrtf(fmaxf(r2, 1e-24f));
        const float r  = r2 * rs;
        const float x = vx * rs, y = vy * rs, z = vz * rs;
        const float t    = 11.0f * r;
        const int   k0   = (int)t;
        const float frac = t - (float)k0;
        float ea = 0.0f, eb = 0.0f;
        if (k0 >= 1 && k0 <= 10) {
            const float da = fmaf(-frac, frac, 1.0f);
            if (da > 0.0226f) ea = KTOT * __expf(-2.0f * fast_rcp(da));
        }
        if (k0 <= 9) {
            const float db = frac * (2.0f - frac);
            if (db > 0.0226f) eb = KTOT * __expf(-2.0f * fast_rcp(db));
        }
        const int ra = min(max(k0 - 1, 0), 9);
        const int rb = min(k0, 9);
        const float4* rowA = &sW1[ra][0];
        const float4* rowB = &sW1[rb][0];
        float wv0 = 0.0f, wv1 = 0.0f, wv2 = 0.0f;
#pragma unroll
        for (int q = 0; q < 4; ++q) {
            const float4 A = rowA[q];
            const float4 B = rowB[q];
            float h;
            h = fmaxf(fmaf(ea, A.x, eb * B.x), 0.0f);
            wv0 = fmaf(h, w2r[4 * q + 0][0], wv0); wv1 = fmaf(h, w2r[4 * q + 0][1], wv1); wv2 = fmaf(h, w2r[4 * q + 0][2], wv2);
            h = fmaxf(fmaf(ea, A.y, eb * B.y), 0.0f);
            wv0 = fmaf(h, w2r[4 * q + 1][0], wv0); wv1 = fmaf(h, w2r[4 * q + 1][1], wv1); wv2 = fmaf(h, w2r[4 * q + 1][2], wv2);
            h = fmaxf(fmaf(ea, A.z, eb * B.z), 0.0f);
            wv0 = fmaf(h, w2r[4 * q + 2][0], wv0); wv1 = fmaf(h, w2r[4 * q + 2][1], wv1); wv2 = fmaf(h, w2r[4 * q + 2][2], wv2);
            h = fmaxf(fmaf(ea, A.w, eb * B.w), 0.0f);
            wv0 = fmaf(h, w2r[4 * q + 3][0], wv0); wv1 = fmaf(h, w2r[4 * q + 3][1], wv1); wv2 = fmaf(h, w2r[4 * q + 3][2], wv2);
        }
        const float f0 = f[0], f1 = f[1], f2 = f[2], f3 = f[3], f4 = f[4];
        const float f5 = f[5], f6 = f[6], f7 = f[7], f8 = f[8];
        const float dots0 = f0;
        const float dots1 = S3 * fmaf(f1, x, fmaf(f2, y, f3 * z));
        const float xx = x * x, yy = y * y, zz = z * z;
        const float sh20 = S5 * S3 * x * z;
        const float sh21 = S5 * S3 * x * y;
        const float sh22 = S5 * (yy - 0.5f * (xx + zz));
        const float sh23 = S5 * S3 * y * z;
        const float sh24 = S5 * 0.5f * S3 * (zz - xx);
        const float dots2 = fmaf(f4, sh20, fmaf(f5, sh21, fmaf(f6, sh22, fmaf(f7, sh23, f8 * sh24))));
        acc = fmaf(wv0, dots0, acc);
        acc = fmaf(wv1, dots1, acc);
        acc = fmaf(wv2, dots2, acc);
    }
#pragma unroll
    for (int off = 1; off < 64; off <<= 1)
        acc += __shfl_xor(acc, off, 64);
    __shared__ float wsum[NTHREADS / 64];
    const int lane = tid & 63, wid = tid >> 6;
    if (lane == 0) wsum[wid] = acc;
    __syncthreads();
    if (tid == 0) {
        float ssum = 0.0f;
#pragma unroll
        for (int w = 0; w < NTHREADS / 64; ++w) ssum += wsum[w];
        block_sums[blockIdx.x] = ssum;
    }
}

__global__ __launch_bounds__(256) void final_reduce_kernel(
    const float* __restrict__ block_sums, float* __restrict__ out, int n)
{
    const int tid = threadIdx.x;
    float acc = 0.0f;
    for (int i = tid; i < n; i += 256) acc += block_sums[i];
#pragma unroll
    for (int off = 1; off < 64; off <<= 1)
        acc += __shfl_xor(acc, off, 64);
    __shared__ float wsum[4];
    if ((tid & 63) == 0) wsum[tid >> 6] = acc;
    __syncthreads();
    if (tid == 0) out[0] = wsum[0] + wsum[1] + wsum[2] + wsum[3];
}

extern "C" void kernel_launch(void* const* d_in, const int* in_sizes, int n_in,
                              void* d_out, int out_size, void* d_ws, size_t ws_size,
                              hipStream_t stream) {
    const float* node_feats = (const float*)d_in[0];
    const float* edge_vec   = (const float*)d_in[1];
    const float* W1         = (const float*)d_in[2];
    const float* W2         = (const float*)d_in[3];
    const int*   edge_src   = (const int*)d_in[4];
    // d_in[5] (edge_dst) unused: segment_sum().sum() == plain sum over edges.
    const int n_edges = in_sizes[4];
    const int n_nodes = in_sizes[0] / 9;

    // ws layout: [block_sums: 32KB][tableA: N*16B][tableB: N*2B]
    float* block_sums = (float*)d_ws;
    const size_t tabA_off = 32768;
    const size_t tabB_off = tabA_off + (size_t)n_nodes * 16;
    const size_t need     = tabB_off + (size_t)n_nodes * 2;

    if (ws_size >= need) {
        uint4*  tableA = (uint4*)((char*)d_ws + tabA_off);
        __half* tableB = (__half*)((char*)d_ws + tabB_off);
        pack_feats_kernel<<<(n_nodes + 255) / 256, 256, 0, stream>>>(
            node_feats, tableA, tableB, n_nodes);
        edge_sum_packed<<<MAIN_NBLOCKS, NTHREADS, 0, stream>>>(
            (const float4*)edge_vec, (const int4*)edge_src, tableA, tableB,
            W1, W2, block_sums, n_edges);
        final_reduce_kernel<<<1, 256, 0, stream>>>(block_sums, (float*)d_out, MAIN_NBLOCKS);
    } else {
        edge_sum_fallback<<<FB_NBLOCKS, NTHREADS, 0, stream>>>(
            node_feats, edge_vec, W1, W2, edge_src, block_sums, n_edges);
        final_reduce_kernel<<<1, 256, 0, stream>>>(block_sums, (float*)d_out, FB_NBLOCKS);
    }
}

// Round 6
// 58.603 us; speedup vs baseline: 3.5546x; 3.5546x over previous
//
#include <hip/hip_runtime.h>
#include <hip/hip_fp16.h>

#define NTHREADS 256
#define NBLOCKS 2048

// Folded constants:
//   KTOT = sqrt(2) * 1.14136 * e^2     (sqrt(10) in emb cancels /sqrt(10) before relu;
//                                       relu positively homogeneous -> sqrt(2) folds in)
//   CL_l = PATH_C_l * 0.25 * (1/sqrt(10))   (w = h@W2/sqrt(16), node scale 1/sqrt(10))
//   SH scale factors (S3, S5*S3, S5, 0.5*S5*S3) folded into the packed fp16 table.
#define KTOT 11.9269705f
#define CL0  0.04564355f
#define CL1  0.02635231f
#define CL2  0.02041241f
#define S3   1.7320508f
#define S5   2.2360680f

__device__ __forceinline__ float fast_rcp(float x) { return __builtin_amdgcn_rcpf(x); }

// ---------- prep: node_feats [N][9] f32 -> tableA [N][8] f16 (16B, SH-scaled) + tableB [N] f16 ----------
__global__ __launch_bounds__(256) void pack_feats_kernel(
    const float* __restrict__ nf, uint4* __restrict__ tableA,
    __half* __restrict__ tableB, int n_nodes)
{
    const int n = blockIdx.x * 256 + threadIdx.x;
    if (n >= n_nodes) return;
    const float* f = nf + 9 * (size_t)n;
    unsigned u[4];
    {
        __half2 h; h.x = __float2half_rn(f[0]);        h.y = __float2half_rn(f[1] * S3);
        u[0] = *reinterpret_cast<unsigned*>(&h);
    }
    {
        __half2 h; h.x = __float2half_rn(f[2] * S3);   h.y = __float2half_rn(f[3] * S3);
        u[1] = *reinterpret_cast<unsigned*>(&h);
    }
    {
        __half2 h; h.x = __float2half_rn(f[4] * (S5 * S3)); h.y = __float2half_rn(f[5] * (S5 * S3));
        u[2] = *reinterpret_cast<unsigned*>(&h);
    }
    {
        __half2 h; h.x = __float2half_rn(f[6] * S5);   h.y = __float2half_rn(f[7] * (S5 * S3));
        u[3] = *reinterpret_cast<unsigned*>(&h);
    }
    tableA[n] = make_uint4(u[0], u[1], u[2], u[3]);
    tableB[n] = __float2half_rn(f[8] * (0.5f * S5 * S3));
}

__device__ __forceinline__ float2 cvt2(unsigned u) {
    __half2 h = *reinterpret_cast<__half2*>(&u);
    return __half22float2(h);
}

// ---------- per-edge term; g0/f8p are SH-prescaled gathered feats; w2r has CL folded ----------
__device__ __forceinline__ float edge_term(
    float vx, float vy, float vz, uint4 g0, float f8p,
    const float4* __restrict__ sW1v, const float (&w2r)[16][3])
{
    const float r2 = fmaf(vx, vx, fmaf(vy, vy, vz * vz));
    const float rs = rsqrtf(fmaxf(r2, 1e-24f));
    const float r  = r2 * rs;
    const float x = vx * rs, y = vy * rs, z = vz * rs;

    // radial smooth_finite: <=2 active bases, no inf anywhere
    const float t    = 11.0f * r;
    const int   k0   = (int)t;
    const float frac = t - (float)k0;
    float ea = 0.0f, eb = 0.0f;
    if (k0 >= 1 && k0 <= 10) {
        const float da = fmaf(-frac, frac, 1.0f);          // 1 - frac^2
        if (da > 0.0226f) ea = KTOT * __expf(-2.0f * fast_rcp(da));
    }
    if (k0 <= 9) {
        const float db = frac * (2.0f - frac);
        if (db > 0.0226f) eb = KTOT * __expf(-2.0f * fast_rcp(db));
    }

    const int ra = min(max(k0 - 1, 0), 9);
    const int rb = min(k0, 9);
    const float4* rowA = sW1v + ra * 5;
    const float4* rowB = sW1v + rb * 5;
    float wv0 = 0.0f, wv1 = 0.0f, wv2 = 0.0f;
#pragma unroll
    for (int q = 0; q < 4; ++q) {
        const float4 A = rowA[q];
        const float4 B = rowB[q];
        float h;
        h = fmaxf(fmaf(ea, A.x, eb * B.x), 0.0f);
        wv0 = fmaf(h, w2r[4 * q + 0][0], wv0); wv1 = fmaf(h, w2r[4 * q + 0][1], wv1); wv2 = fmaf(h, w2r[4 * q + 0][2], wv2);
        h = fmaxf(fmaf(ea, A.y, eb * B.y), 0.0f);
        wv0 = fmaf(h, w2r[4 * q + 1][0], wv0); wv1 = fmaf(h, w2r[4 * q + 1][1], wv1); wv2 = fmaf(h, w2r[4 * q + 1][2], wv2);
        h = fmaxf(fmaf(ea, A.z, eb * B.z), 0.0f);
        wv0 = fmaf(h, w2r[4 * q + 2][0], wv0); wv1 = fmaf(h, w2r[4 * q + 2][1], wv1); wv2 = fmaf(h, w2r[4 * q + 2][2], wv2);
        h = fmaxf(fmaf(ea, A.w, eb * B.w), 0.0f);
        wv0 = fmaf(h, w2r[4 * q + 3][0], wv0); wv1 = fmaf(h, w2r[4 * q + 3][1], wv1); wv2 = fmaf(h, w2r[4 * q + 3][2], wv2);
    }

    const float2 f01 = cvt2(g0.x);   // f0,       S3*f1
    const float2 f23 = cvt2(g0.y);   // S3*f2,    S3*f3
    const float2 f45 = cvt2(g0.z);   // S5S3*f4,  S5S3*f5
    const float2 f67 = cvt2(g0.w);   // S5*f6,    S5S3*f7

    const float dots0 = f01.x;
    const float dots1 = fmaf(f01.y, x, fmaf(f23.x, y, f23.y * z));
    const float xx = x * x, yy = y * y, zz = z * z;
    const float dots2 = fmaf(f45.x, x * z, fmaf(f45.y, x * y,
                        fmaf(f67.x, fmaf(-0.5f, xx + zz, yy),
                        fmaf(f67.y, y * z, f8p * (zz - xx)))));

    return fmaf(wv0, dots0, fmaf(wv1, dots1, wv2 * dots2));
}

// ---------- main: round-3 structure (plain grid-stride, 4 edges/iter) + split tables ----------
__global__ __launch_bounds__(NTHREADS) void edge_sum_packed(
    const float4* __restrict__ ev4,
    const int4*   __restrict__ src4,
    const uint4*  __restrict__ tableA,
    const __half* __restrict__ tableB,
    const float*  __restrict__ W1,
    const float*  __restrict__ W2,
    float*        __restrict__ block_sums,
    int n_edges)
{
    __shared__ float4 sW1[10][5];
    float* sW1f = reinterpret_cast<float*>(sW1);
    const int tid = threadIdx.x;
    if (tid < 160) {
        sW1f[(tid >> 4) * 20 + (tid & 15)] = W1[tid];
    } else if (tid < 200) {
        const int i = tid - 160;
        sW1f[(i >> 2) * 20 + 16 + (i & 3)] = 0.0f;
    }
    __syncthreads();

    // W2 with CL folded (lane-uniform loads -> compiler scalarizes)
    float w2r[16][3];
#pragma unroll
    for (int j = 0; j < 16; ++j) {
        w2r[j][0] = W2[j * 3 + 0] * CL0;
        w2r[j][1] = W2[j * 3 + 1] * CL1;
        w2r[j][2] = W2[j * 3 + 2] * CL2;
    }

    const float4* sW1v = &sW1[0][0];
    float acc = 0.0f;
    const int n_groups = (n_edges + 3) >> 2;
    const int stride = gridDim.x * blockDim.x;
    for (int g = blockIdx.x * blockDim.x + tid; g < n_groups; g += stride) {
        const int e0 = g << 2;
        if (e0 + 3 < n_edges) {
            // all independent loads issued together; compiler schedules
            const float4 a = ev4[3 * (size_t)g + 0];
            const float4 b = ev4[3 * (size_t)g + 1];
            const float4 c = ev4[3 * (size_t)g + 2];
            const int4   s = src4[g];
            const uint4 gA0 = tableA[s.x];
            const uint4 gA1 = tableA[s.y];
            const uint4 gA2 = tableA[s.z];
            const uint4 gA3 = tableA[s.w];
            const float f80 = __half2float(tableB[s.x]);
            const float f81 = __half2float(tableB[s.y]);
            const float f82 = __half2float(tableB[s.z]);
            const float f83 = __half2float(tableB[s.w]);
            acc += edge_term(a.x, a.y, a.z, gA0, f80, sW1v, w2r);
            acc += edge_term(a.w, b.x, b.y, gA1, f81, sW1v, w2r);
            acc += edge_term(b.z, b.w, c.x, gA2, f82, sW1v, w2r);
            acc += edge_term(c.y, c.z, c.w, gA3, f83, sW1v, w2r);
        } else {
            const float* evf  = reinterpret_cast<const float*>(ev4);
            const int*   srci = reinterpret_cast<const int*>(src4);
            for (int e = e0; e < n_edges; ++e) {
                const int si = srci[e];
                acc += edge_term(evf[3 * (size_t)e], evf[3 * (size_t)e + 1],
                                 evf[3 * (size_t)e + 2], tableA[si],
                                 __half2float(tableB[si]), sW1v, w2r);
            }
        }
    }

    // deterministic block reduction
#pragma unroll
    for (int off = 1; off < 64; off <<= 1)
        acc += __shfl_xor(acc, off, 64);
    __shared__ float wsum[NTHREADS / 64];
    const int lane = tid & 63, wid = tid >> 6;
    if (lane == 0) wsum[wid] = acc;
    __syncthreads();
    if (tid == 0) {
        float ssum = 0.0f;
#pragma unroll
        for (int w = 0; w < NTHREADS / 64; ++w) ssum += wsum[w];
        block_sums[blockIdx.x] = ssum;
    }
}

// ---------- fallback (round-2 proven path, f32 scalar gather) ----------
__global__ __launch_bounds__(NTHREADS) void edge_sum_fallback(
    const float* __restrict__ node_feats,
    const float* __restrict__ edge_vec,
    const float* __restrict__ W1,
    const float* __restrict__ W2,
    const int*   __restrict__ edge_src,
    float*       __restrict__ block_sums,
    int n_edges)
{
    __shared__ float4 sW1[10][5];
    float* sW1f = reinterpret_cast<float*>(sW1);
    const int tid = threadIdx.x;
    if (tid < 160) {
        sW1f[(tid >> 4) * 20 + (tid & 15)] = W1[tid];
    } else if (tid < 200) {
        const int i = tid - 160;
        sW1f[(i >> 2) * 20 + 16 + (i & 3)] = 0.0f;
    }
    __syncthreads();

    float w2r[16][3];
#pragma unroll
    for (int j = 0; j < 16; ++j) {
        w2r[j][0] = W2[j * 3 + 0] * CL0;
        w2r[j][1] = W2[j * 3 + 1] * CL1;
        w2r[j][2] = W2[j * 3 + 2] * CL2;
    }

    float acc = 0.0f;
    const int stride = gridDim.x * blockDim.x;
    for (int e = blockIdx.x * blockDim.x + tid; e < n_edges; e += stride) {
        const float vx = edge_vec[3 * (size_t)e + 0];
        const float vy = edge_vec[3 * (size_t)e + 1];
        const float vz = edge_vec[3 * (size_t)e + 2];
        const int   src = edge_src[e];
        const float* f = node_feats + 9 * (size_t)src;
        const float r2 = fmaf(vx, vx, fmaf(vy, vy, vz * vz));
        const float rs = rsqrtf(fmaxf(r2, 1e-24f));
        const float r  = r2 * rs;
        const float x = vx * rs, y = vy * rs, z = vz * rs;
        const float t    = 11.0f * r;
        const int   k0   = (int)t;
        const float frac = t - (float)k0;
        float ea = 0.0f, eb = 0.0f;
        if (k0 >= 1 && k0 <= 10) {
            const float da = fmaf(-frac, frac, 1.0f);
            if (da > 0.0226f) ea = KTOT * __expf(-2.0f * fast_rcp(da));
        }
        if (k0 <= 9) {
            const float db = frac * (2.0f - frac);
            if (db > 0.0226f) eb = KTOT * __expf(-2.0f * fast_rcp(db));
        }
        const int ra = min(max(k0 - 1, 0), 9);
        const int rb = min(k0, 9);
        const float4* rowA = &sW1[ra][0];
        const float4* rowB = &sW1[rb][0];
        float wv0 = 0.0f, wv1 = 0.0f, wv2 = 0.0f;
#pragma unroll
        for (int q = 0; q < 4; ++q) {
            const float4 A = rowA[q];
            const float4 B = rowB[q];
            float h;
            h = fmaxf(fmaf(ea, A.x, eb * B.x), 0.0f);
            wv0 = fmaf(h, w2r[4 * q + 0][0], wv0); wv1 = fmaf(h, w2r[4 * q + 0][1], wv1); wv2 = fmaf(h, w2r[4 * q + 0][2], wv2);
            h = fmaxf(fmaf(ea, A.y, eb * B.y), 0.0f);
            wv0 = fmaf(h, w2r[4 * q + 1][0], wv0); wv1 = fmaf(h, w2r[4 * q + 1][1], wv1); wv2 = fmaf(h, w2r[4 * q + 1][2], wv2);
            h = fmaxf(fmaf(ea, A.z, eb * B.z), 0.0f);
            wv0 = fmaf(h, w2r[4 * q + 2][0], wv0); wv1 = fmaf(h, w2r[4 * q + 2][1], wv1); wv2 = fmaf(h, w2r[4 * q + 2][2], wv2);
            h = fmaxf(fmaf(ea, A.w, eb * B.w), 0.0f);
            wv0 = fmaf(h, w2r[4 * q + 3][0], wv0); wv1 = fmaf(h, w2r[4 * q + 3][1], wv1); wv2 = fmaf(h, w2r[4 * q + 3][2], wv2);
        }
        const float f0 = f[0], f1 = f[1], f2 = f[2], f3 = f[3], f4 = f[4];
        const float f5 = f[5], f6 = f[6], f7 = f[7], f8 = f[8];
        const float dots0 = f0;
        const float dots1 = S3 * fmaf(f1, x, fmaf(f2, y, f3 * z));
        const float xx = x * x, yy = y * y, zz = z * z;
        const float sh20 = S5 * S3 * x * z;
        const float sh21 = S5 * S3 * x * y;
        const float sh22 = S5 * (yy - 0.5f * (xx + zz));
        const float sh23 = S5 * S3 * y * z;
        const float sh24 = S5 * 0.5f * S3 * (zz - xx);
        const float dots2 = fmaf(f4, sh20, fmaf(f5, sh21, fmaf(f6, sh22, fmaf(f7, sh23, f8 * sh24))));
        acc = fmaf(wv0, dots0, acc);
        acc = fmaf(wv1, dots1, acc);
        acc = fmaf(wv2, dots2, acc);
    }
#pragma unroll
    for (int off = 1; off < 64; off <<= 1)
        acc += __shfl_xor(acc, off, 64);
    __shared__ float wsum[NTHREADS / 64];
    const int lane = tid & 63, wid = tid >> 6;
    if (lane == 0) wsum[wid] = acc;
    __syncthreads();
    if (tid == 0) {
        float ssum = 0.0f;
#pragma unroll
        for (int w = 0; w < NTHREADS / 64; ++w) ssum += wsum[w];
        block_sums[blockIdx.x] = ssum;
    }
}

__global__ __launch_bounds__(256) void final_reduce_kernel(
    const float* __restrict__ block_sums, float* __restrict__ out, int n)
{
    const int tid = threadIdx.x;
    float acc = 0.0f;
    for (int i = tid; i < n; i += 256) acc += block_sums[i];
#pragma unroll
    for (int off = 1; off < 64; off <<= 1)
        acc += __shfl_xor(acc, off, 64);
    __shared__ float wsum[4];
    if ((tid & 63) == 0) wsum[tid >> 6] = acc;
    __syncthreads();
    if (tid == 0) out[0] = wsum[0] + wsum[1] + wsum[2] + wsum[3];
}

extern "C" void kernel_launch(void* const* d_in, const int* in_sizes, int n_in,
                              void* d_out, int out_size, void* d_ws, size_t ws_size,
                              hipStream_t stream) {
    const float* node_feats = (const float*)d_in[0];
    const float* edge_vec   = (const float*)d_in[1];
    const float* W1         = (const float*)d_in[2];
    const float* W2         = (const float*)d_in[3];
    const int*   edge_src   = (const int*)d_in[4];
    // d_in[5] (edge_dst) unused: segment_sum().sum() == plain sum over edges.
    const int n_edges = in_sizes[4];
    const int n_nodes = in_sizes[0] / 9;

    // ws layout: [block_sums: 32KB][tableA: N*16B][tableB: N*2B]
    float* block_sums = (float*)d_ws;
    const size_t tabA_off = 32768;
    const size_t tabB_off = tabA_off + (size_t)n_nodes * 16;
    const size_t need     = tabB_off + (size_t)n_nodes * 2;

    if (ws_size >= need) {
        uint4*  tableA = (uint4*)((char*)d_ws + tabA_off);
        __half* tableB = (__half*)((char*)d_ws + tabB_off);
        pack_feats_kernel<<<(n_nodes + 255) / 256, 256, 0, stream>>>(
            node_feats, tableA, tableB, n_nodes);
        edge_sum_packed<<<NBLOCKS, NTHREADS, 0, stream>>>(
            (const float4*)edge_vec, (const int4*)edge_src, tableA, tableB,
            W1, W2, block_sums, n_edges);
        final_reduce_kernel<<<1, 256, 0, stream>>>(block_sums, (float*)d_out, NBLOCKS);
    } else {
        edge_sum_fallback<<<NBLOCKS, NTHREADS, 0, stream>>>(
            node_feats, edge_vec, W1, W2, edge_src, block_sums, n_edges);
        final_reduce_kernel<<<1, 256, 0, stream>>>(block_sums, (float*)d_out, NBLOCKS);
    }
}